// Round 14
// baseline (264.035 us; speedup 1.0000x reference)
//
#include <hip/hip_runtime.h>

#define NN 8192
#define CIN 32
#define COUT 64
#define KF 5

typedef __attribute__((ext_vector_type(8))) short bf16x8_t;
typedef __attribute__((ext_vector_type(4))) float f32x4_t;

typedef const __attribute__((address_space(1))) void* as1_t;
typedef __attribute__((address_space(3))) void* as3_t;
__device__ __forceinline__ void gll16(const void* g, void* l) {
    __builtin_amdgcn_global_load_lds((as1_t)g, (as3_t)l, 16, 0, 0);
}

// fp32 -> bf16 RNE
__device__ __forceinline__ short f2bf(float f) {
    unsigned u = __builtin_bit_cast(unsigned, f);
    unsigned r = (u + 0x7FFFu + ((u >> 16) & 1u)) >> 16;
    return (short)(unsigned short)r;
}

__device__ __forceinline__ bf16x8_t cvt8v(f32x4_t a, f32x4_t b) {
    bf16x8_t v;
    v[0] = f2bf(a[0]); v[1] = f2bf(a[1]); v[2] = f2bf(a[2]); v[3] = f2bf(a[3]);
    v[4] = f2bf(b[0]); v[5] = f2bf(b[1]); v[6] = f2bf(b[2]); v[7] = f2bf(b[3]);
    return v;
}

// x fp32 -> bf16
__global__ void cvt_kernel(const float* __restrict__ src, short* __restrict__ dst) {
    int idx = blockIdx.x * 256 + threadIdx.x;
    float4 v = reinterpret_cast<const float4*>(src)[idx];
    short4 o;
    o.x = f2bf(v.x); o.y = f2bf(v.y); o.z = f2bf(v.z); o.w = f2bf(v.w);
    reinterpret_cast<short4*>(dst)[idx] = o;
}

// ---- cvtL: pure stream L fp32 -> Lb bf16 in tiled chunk layout.
// Block = tile t (16 rows) x 8 waves (wave: K-range 1024 = 16 chunks of 64 cols).
// Reads: lane (g,r): row (i0+r), cols kw + c*64 + {g*8, 32+g*8} -> 128B runs/row. NT.
// Writes: wave output contiguous 32KB; per chunk 2x 1KB fully-linear stores.
__global__ __launch_bounds__(512, 8) void cvtL_kernel(
    const float* __restrict__ L, char* __restrict__ LbC)
{
    const int tid = threadIdx.x, wave = tid >> 6, lane = tid & 63;
    const int g = lane >> 4, r = lane & 15;
    const int t = blockIdx.x, i0 = t * 16;
    const int kw = wave * 1024;

    const float* Lr = L + (size_t)(i0 + r) * NN + kw + g * 8;
    char* LbW = LbC + (size_t)t * 262144 + wave * 32768 + lane * 16;

#pragma unroll 2
    for (int c = 0; c < 16; ++c) {
        const float* p = Lr + c * 64;
        f32x4_t a0 = __builtin_nontemporal_load(reinterpret_cast<const f32x4_t*>(p));
        f32x4_t a1 = __builtin_nontemporal_load(reinterpret_cast<const f32x4_t*>(p) + 1);
        f32x4_t b0 = __builtin_nontemporal_load(reinterpret_cast<const f32x4_t*>(p + 32));
        f32x4_t b1 = __builtin_nontemporal_load(reinterpret_cast<const f32x4_t*>(p + 32) + 1);
        *(bf16x8_t*)(LbW + c * 2048)        = cvt8v(a0, a1);   // kk=0
        *(bf16x8_t*)(LbW + c * 2048 + 1024) = cvt8v(b0, b1);   // kk=1
    }
}

// D layout (m89): col=lane&15 -> i, row=(lane>>4)*4+reg -> c
__device__ __forceinline__ void stash_partials(float* red, int wave, int g, int r,
                                               const f32x4_t& acc0, const f32x4_t& acc1) {
    const int base = wave * 512 + g * 64 + r;
#pragma unroll
    for (int t = 0; t < 4; ++t) {
        red[base + t * 16]       = acc0[t];
        red[base + t * 16 + 256] = acc1[t];
    }
}

__device__ __forceinline__ float reduce8(const float* red, int tid) {
    float s = red[tid];
#pragma unroll
    for (int w = 1; w < 8; ++w) s += red[w * 512 + tid];
    return s;
}

// Mid-pass core (R9-proven): wave-private K 1024 = 16 chunks of 64 cols, depth-2 DMA ring.
// LbW must include the wave's 32KB offset (bug fixed from R13).
__device__ __forceinline__ void mid_core(const char* __restrict__ LbW,
                                         const short* __restrict__ Abase,
                                         int wave, int lane, char* stg,
                                         f32x4_t& acc0, f32x4_t& acc1)
{
    const int g = lane >> 4, r = lane & 15;
    const int kw = wave * 1024;
    const char* srcL = LbW + lane * 16;
    const short* sA0 = Abase + (size_t)(lane & 31) * NN + kw + (lane >> 5) * 8;

#pragma unroll
    for (int c0 = 0; c0 < 2; ++c0) {     // prologue: chunks 0,1 (6 DMA each)
        char* Ld = stg + c0 * 6144;
        char* Ad = Ld + 2048;
        gll16(srcL + c0 * 2048,        Ld);
        gll16(srcL + c0 * 2048 + 1024, Ld + 1024);
#pragma unroll
        for (int j = 0; j < 4; ++j) gll16(sA0 + c0 * 64 + j * 16, Ad + j * 1024);
    }

    for (int c = 0; c < 16; ++c) {
        if (c < 15) asm volatile("s_waitcnt vmcnt(6)" ::: "memory");
        else        asm volatile("s_waitcnt vmcnt(0)" ::: "memory");
        const char* Ld = stg + (c & 1) * 6144;
        const char* Ad = Ld + 2048;
#pragma unroll
        for (int kk = 0; kk < 2; ++kk) {
            bf16x8_t b  = *(const bf16x8_t*)(Ld + (kk * 4 + g) * 256 + r * 16);
            bf16x8_t a0 = *(const bf16x8_t*)(Ad + (kk * 4 + g) * 512 + r * 16);
            bf16x8_t a1 = *(const bf16x8_t*)(Ad + (kk * 4 + g) * 512 + 256 + r * 16);
            acc0 = __builtin_amdgcn_mfma_f32_16x16x32_bf16(a0, b, acc0, 0, 0, 0);
            acc1 = __builtin_amdgcn_mfma_f32_16x16x32_bf16(a1, b, acc1, 0, 0, 0);
        }
        if (c < 14) {
            asm volatile("s_waitcnt lgkmcnt(0)" ::: "memory");
            const int cn = c + 2;
            char* Ldn = stg + (cn & 1) * 6144;
            char* Adn = Ldn + 2048;
            gll16(srcL + cn * 2048,        Ldn);
            gll16(srcL + cn * 2048 + 1024, Ldn + 1024);
#pragma unroll
            for (int j = 0; j < 4; ++j) gll16(sA0 + cn * 64 + j * 16, Adn + j * 1024);
        }
    }
}

// ---- Unified pass (T1/T2/T3): T = alpha*(A @ Lb^T) - (Tprev?); fp32+bf16 out
__global__ __launch_bounds__(512, 2) void pass_kernel(
    const char* __restrict__ LbC, const short* __restrict__ A,
    const float* __restrict__ Tprev, const float alpha,
    float* __restrict__ Tf, short* __restrict__ Tb)
{
    __shared__ float red[4096];
    __shared__ __align__(16) char stg[8][12288];
    const int tid = threadIdx.x, wave = tid >> 6, lane = tid & 63;
    const int g = lane >> 4, r = lane & 15;
    const int t = blockIdx.x, i0 = t * 16;

    f32x4_t acc0 = {0.f,0.f,0.f,0.f}, acc1 = {0.f,0.f,0.f,0.f};
    mid_core(LbC + (size_t)t * 262144 + wave * 32768, A, wave, lane, stg[wave], acc0, acc1);

    stash_partials(red, wave, g, r, acc0, acc1);
    __syncthreads();
    const int c = tid >> 4, il = tid & 15;
    const size_t off = (size_t)c * NN + i0 + il;
    float val = alpha * reduce8(red, tid);
    if (Tprev) val -= Tprev[off];
    Tf[off] = val;
    Tb[off] = f2bf(val);
}

// ---- Pass 4 + fused final einsum (T4 stays in LDS)
__global__ __launch_bounds__(512, 2) void pass4_kernel(
    const char* __restrict__ LbC, const short* __restrict__ A,
    const float* __restrict__ Tf2, const float* __restrict__ x,
    const float* __restrict__ Tf1, const float* __restrict__ Tf3,
    const float* __restrict__ theta, const float* __restrict__ bias,
    float* __restrict__ y)
{
    __shared__ float red[4096];
    __shared__ __align__(16) char stg[8][12288];
    const int tid = threadIdx.x, wave = tid >> 6, lane = tid & 63;
    const int g = lane >> 4, r = lane & 15;
    const int t = blockIdx.x, i0 = t * 16;

    f32x4_t acc0 = {0.f,0.f,0.f,0.f}, acc1 = {0.f,0.f,0.f,0.f};
    mid_core(LbC + (size_t)t * 262144 + wave * 32768, A, wave, lane, stg[wave], acc0, acc1);

    stash_partials(red, wave, g, r, acc0, acc1);
    __syncthreads();
    {   // T4 column -> red[tid] (own-slot overwrite, safe)
        const int c = tid >> 4, il = tid & 15;
        red[tid] = 2.0f * reduce8(red, tid) - Tf2[(size_t)c * NN + i0 + il];
    }
    __syncthreads();

    const int o = tid >> 4, il = tid & 15;
    float a0 = bias[o], a1 = bias[o + 32];
    for (int cc = 0; cc < CIN; ++cc) {
        const size_t off = (size_t)cc * NN + i0 + il;
        const float t0 = x[off], t1 = Tf1[off], t2 = Tf2[off], t3 = Tf3[off];
        const float t4 = red[cc * 16 + il];
        const float* th0 = theta + ((size_t)o * CIN + cc) * KF;
        const float* th1 = theta + ((size_t)(o + 32) * CIN + cc) * KF;
        a0 += t0 * th0[0] + t1 * th0[1] + t2 * th0[2] + t3 * th0[3] + t4 * th0[4];
        a1 += t0 * th1[0] + t1 * th1[1] + t2 * th1[2] + t3 * th1[3] + t4 * th1[4];
    }
    y[(size_t)o * NN + i0 + il]        = a0;
    y[(size_t)(o + 32) * NN + i0 + il] = a1;
}

extern "C" void kernel_launch(void* const* d_in, const int* in_sizes, int n_in,
                              void* d_out, int out_size, void* d_ws, size_t ws_size,
                              hipStream_t stream) {
    const float* L     = (const float*)d_in[0];
    const float* x     = (const float*)d_in[1];
    const float* theta = (const float*)d_in[2];
    const float* bias  = (const float*)d_in[3];
    float* y = (float*)d_out;

    const size_t TE = (size_t)CIN * NN;
    const size_t LE = (size_t)NN * NN;

    // ws: Lb tiled (128MB) | Tf1..Tf3 (1MB ea) | Tb0..Tb3 (0.5MB ea)
    char*  LbC = (char*)d_ws;
    float* Tf1 = (float*)(LbC + LE * 2);
    float* Tf2 = Tf1 + TE;
    float* Tf3 = Tf2 + TE;
    short* Tb0 = (short*)(Tf3 + TE);
    short* Tb1 = Tb0 + TE;
    short* Tb2 = Tb1 + TE;
    short* Tb3 = Tb2 + TE;

    cvt_kernel<<<256, 256, 0, stream>>>(x, Tb0);
    cvtL_kernel<<<NN / 16, 512, 0, stream>>>(L, LbC);
    pass_kernel<<<NN / 16, 512, 0, stream>>>(LbC, Tb0, nullptr, 1.0f, Tf1, Tb1); // T1
    pass_kernel<<<NN / 16, 512, 0, stream>>>(LbC, Tb1, x,       2.0f, Tf2, Tb2); // T2
    pass_kernel<<<NN / 16, 512, 0, stream>>>(LbC, Tb2, Tf1,     2.0f, Tf3, Tb3); // T3
    pass4_kernel<<<NN / 16, 512, 0, stream>>>(LbC, Tb3, Tf2, x, Tf1, Tf3,
                                              theta, bias, y);                   // T4 + einsum
}

// Round 15
// 244.552 us; speedup vs baseline: 1.0797x; 1.0797x over previous
//
#include <hip/hip_runtime.h>

#define NN 8192
#define CIN 32
#define COUT 64
#define KF 5

typedef __attribute__((ext_vector_type(8))) short bf16x8_t;
typedef __attribute__((ext_vector_type(4))) float f32x4_t;

typedef const __attribute__((address_space(1))) void* as1_t;
typedef __attribute__((address_space(3))) void* as3_t;
__device__ __forceinline__ void gll16(const void* g, void* l) {
    __builtin_amdgcn_global_load_lds((as1_t)g, (as3_t)l, 16, 0, 0);
}

// fp32 -> bf16 RNE
__device__ __forceinline__ short f2bf(float f) {
    unsigned u = __builtin_bit_cast(unsigned, f);
    unsigned r = (u + 0x7FFFu + ((u >> 16) & 1u)) >> 16;
    return (short)(unsigned short)r;
}

__device__ __forceinline__ bf16x8_t cvt8v(f32x4_t a, f32x4_t b) {
    bf16x8_t v;
    v[0] = f2bf(a[0]); v[1] = f2bf(a[1]); v[2] = f2bf(a[2]); v[3] = f2bf(a[3]);
    v[4] = f2bf(b[0]); v[5] = f2bf(b[1]); v[6] = f2bf(b[2]); v[7] = f2bf(b[3]);
    return v;
}

// x fp32 -> bf16
__global__ void cvt_kernel(const float* __restrict__ src, short* __restrict__ dst) {
    int idx = blockIdx.x * 256 + threadIdx.x;
    float4 v = reinterpret_cast<const float4*>(src)[idx];
    short4 o;
    o.x = f2bf(v.x); o.y = f2bf(v.y); o.z = f2bf(v.z); o.w = f2bf(v.w);
    reinterpret_cast<short4*>(dst)[idx] = o;
}

// D layout (m89): col=lane&15 -> i, row=(lane>>4)*4+reg -> c
__device__ __forceinline__ void stash_partials(float* red, int wave, int g, int r,
                                               const f32x4_t& acc0, const f32x4_t& acc1) {
    const int base = wave * 512 + g * 64 + r;
#pragma unroll
    for (int t = 0; t < 4; ++t) {
        red[base + t * 16]       = acc0[t];
        red[base + t * 16 + 256] = acc1[t];
    }
}

__device__ __forceinline__ float reduce8(const float* red, int tid) {
    float s = red[tid];
#pragma unroll
    for (int w = 1; w < 8; ++w) s += red[w * 512 + tid];
    return s;
}

// ---- Pass 1 (R12-proven): K split 2-way -> grid 1024 -> 32 waves/CU.
// NT fp32 L reads; Lb stored in tiled chunk layout (linear 1KB wave stores).
__global__ __launch_bounds__(512, 8) void pass1_kernel(
    const float* __restrict__ L, const short* __restrict__ Tb0,
    char* __restrict__ LbC, float* __restrict__ part)
{
    __shared__ float red[4096];
    const int tid = threadIdx.x, wave = tid >> 6, lane = tid & 63;
    const int g = lane >> 4, r = lane & 15;
    const int t = blockIdx.x >> 1, h = blockIdx.x & 1;
    const int i0 = t * 16;
    const int kw = h * 4096 + wave * 512;

    const float* Lrow = L   + (size_t)(i0 + r) * NN + kw + g * 8;
    const short* A0   = Tb0 + (size_t)r * NN        + kw + g * 8;
    const short* A1   = Tb0 + (size_t)(r + 16) * NN + kw + g * 8;
    char* LbW = LbC + (size_t)t * 262144 + (size_t)(h * 4 + (wave >> 1)) * 32768
              + (wave & 1) * 16384 + lane * 16;

    f32x4_t acc0 = {0.f,0.f,0.f,0.f}, acc1 = {0.f,0.f,0.f,0.f};
    for (int it = 0; it < 16; ++it) {
        const int jl = it * 32;
        f32x4_t l0 = __builtin_nontemporal_load(reinterpret_cast<const f32x4_t*>(Lrow + jl));
        f32x4_t l1 = __builtin_nontemporal_load(reinterpret_cast<const f32x4_t*>(Lrow + jl) + 1);
        bf16x8_t a0 = *(const bf16x8_t*)(A0 + jl);
        bf16x8_t a1 = *(const bf16x8_t*)(A1 + jl);
        bf16x8_t b = cvt8v(l0, l1);
        *(bf16x8_t*)(LbW + it * 1024) = b;            // linear 1KB store (cached)
        acc0 = __builtin_amdgcn_mfma_f32_16x16x32_bf16(a0, b, acc0, 0, 0, 0);
        acc1 = __builtin_amdgcn_mfma_f32_16x16x32_bf16(a1, b, acc1, 0, 0, 0);
    }

    stash_partials(red, wave, g, r, acc0, acc1);
    __syncthreads();
    const int c = tid >> 4, il = tid & 15;
    part[(size_t)h * CIN * NN + (size_t)c * NN + i0 + il] = reduce8(red, tid);
}

// ---- T1 = part0 + part1 (fixed order); write fp32 + bf16
__global__ __launch_bounds__(256) void combine1_kernel(
    const float* __restrict__ part, float* __restrict__ Tf1, short* __restrict__ Tb1)
{
    const int idx = blockIdx.x * 256 + threadIdx.x;
    const float4 p0 = reinterpret_cast<const float4*>(part)[idx];
    const float4 p1 = reinterpret_cast<const float4*>(part + (size_t)CIN * NN)[idx];
    float4 v;
    v.x = p0.x + p1.x; v.y = p0.y + p1.y; v.z = p0.z + p1.z; v.w = p0.w + p1.w;
    reinterpret_cast<float4*>(Tf1)[idx] = v;
    short4 b;
    b.x = f2bf(v.x); b.y = f2bf(v.y); b.z = f2bf(v.z); b.w = f2bf(v.w);
    reinterpret_cast<short4*>(Tb1)[idx] = b;
}

// Mid-pass core v2: L via depth-2 DMA ring (2KB/chunk), A via PLAIN VGPR loads
// (A is 0.5MB, L2-resident). LDS/wave = 4KB only -> both resident blocks run.
__device__ __forceinline__ void mid_core(const char* __restrict__ LbW,
                                         const short* __restrict__ Abase,
                                         int wave, int lane, char* stg,
                                         f32x4_t& acc0, f32x4_t& acc1)
{
    const int g = lane >> 4, r = lane & 15;
    const int kw = wave * 1024;
    const char* srcL = LbW + lane * 16;
    const short* A0 = Abase + (size_t)r * NN        + kw + g * 8;
    const short* A1 = Abase + (size_t)(r + 16) * NN + kw + g * 8;

    // prologue: L chunks 0,1
    gll16(srcL + 0,    stg + 0);
    gll16(srcL + 1024, stg + 1024);
    gll16(srcL + 2048, stg + 2048);
    gll16(srcL + 3072, stg + 3072);

    for (int c = 0; c < 16; ++c) {
        if (c < 15) asm volatile("s_waitcnt vmcnt(2)" ::: "memory");
        else        asm volatile("s_waitcnt vmcnt(0)" ::: "memory");
        const char* Ld = stg + (c & 1) * 2048;
#pragma unroll
        for (int kk = 0; kk < 2; ++kk) {
            bf16x8_t b  = *(const bf16x8_t*)(Ld + (kk * 4 + g) * 256 + r * 16);
            bf16x8_t a0 = *(const bf16x8_t*)(A0 + c * 64 + kk * 32);
            bf16x8_t a1 = *(const bf16x8_t*)(A1 + c * 64 + kk * 32);
            acc0 = __builtin_amdgcn_mfma_f32_16x16x32_bf16(a0, b, acc0, 0, 0, 0);
            acc1 = __builtin_amdgcn_mfma_f32_16x16x32_bf16(a1, b, acc1, 0, 0, 0);
        }
        if (c < 14) {
            asm volatile("s_waitcnt lgkmcnt(0)" ::: "memory");
            const int cn = c + 2;
            gll16(srcL + cn * 2048,        stg + (cn & 1) * 2048);
            gll16(srcL + cn * 2048 + 1024, stg + (cn & 1) * 2048 + 1024);
        }
    }
}

// ---- Mid passes (2,3): T_next = 2*(Tcur @ Lb^T) - Tprev
__global__ __launch_bounds__(512, 4) void passmid_kernel(
    const char* __restrict__ LbC, const short* __restrict__ A,
    const float* __restrict__ Tprev, float* __restrict__ Tf, short* __restrict__ Tb)
{
    __shared__ float red[4096];
    __shared__ __align__(16) char stg[8][4096];   // 32KB; total LDS 48KB -> 2 blocks/CU
    const int tid = threadIdx.x, wave = tid >> 6, lane = tid & 63;
    const int g = lane >> 4, r = lane & 15;
    const int t = blockIdx.x, i0 = t * 16;

    f32x4_t acc0 = {0.f,0.f,0.f,0.f}, acc1 = {0.f,0.f,0.f,0.f};
    mid_core(LbC + (size_t)t * 262144 + wave * 32768, A, wave, lane, stg[wave], acc0, acc1);

    stash_partials(red, wave, g, r, acc0, acc1);
    __syncthreads();
    const int c = tid >> 4, il = tid & 15;
    const size_t off = (size_t)c * NN + i0 + il;
    const float val = 2.0f * reduce8(red, tid) - Tprev[off];
    Tf[off] = val;
    Tb[off] = f2bf(val);
}

// ---- Pass 4 + fused final einsum (T4 stays in LDS)
__global__ __launch_bounds__(512, 4) void pass4_kernel(
    const char* __restrict__ LbC, const short* __restrict__ A,
    const float* __restrict__ Tf2, const float* __restrict__ x,
    const float* __restrict__ Tf1, const float* __restrict__ Tf3,
    const float* __restrict__ theta, const float* __restrict__ bias,
    float* __restrict__ y)
{
    __shared__ float red[4096];
    __shared__ __align__(16) char stg[8][4096];
    const int tid = threadIdx.x, wave = tid >> 6, lane = tid & 63;
    const int g = lane >> 4, r = lane & 15;
    const int t = blockIdx.x, i0 = t * 16;

    f32x4_t acc0 = {0.f,0.f,0.f,0.f}, acc1 = {0.f,0.f,0.f,0.f};
    mid_core(LbC + (size_t)t * 262144 + wave * 32768, A, wave, lane, stg[wave], acc0, acc1);

    stash_partials(red, wave, g, r, acc0, acc1);
    __syncthreads();
    {   // T4 column -> red[tid] (own-slot overwrite, safe)
        const int c = tid >> 4, il = tid & 15;
        red[tid] = 2.0f * reduce8(red, tid) - Tf2[(size_t)c * NN + i0 + il];
    }
    __syncthreads();

    const int o = tid >> 4, il = tid & 15;
    float a0 = bias[o], a1 = bias[o + 32];
    for (int cc = 0; cc < CIN; ++cc) {
        const size_t off = (size_t)cc * NN + i0 + il;
        const float t0 = x[off], t1 = Tf1[off], t2 = Tf2[off], t3 = Tf3[off];
        const float t4 = red[cc * 16 + il];
        const float* th0 = theta + ((size_t)o * CIN + cc) * KF;
        const float* th1 = theta + ((size_t)(o + 32) * CIN + cc) * KF;
        a0 += t0 * th0[0] + t1 * th0[1] + t2 * th0[2] + t3 * th0[3] + t4 * th0[4];
        a1 += t0 * th1[0] + t1 * th1[1] + t2 * th1[2] + t3 * th1[3] + t4 * th1[4];
    }
    y[(size_t)o * NN + i0 + il]        = a0;
    y[(size_t)(o + 32) * NN + i0 + il] = a1;
}

extern "C" void kernel_launch(void* const* d_in, const int* in_sizes, int n_in,
                              void* d_out, int out_size, void* d_ws, size_t ws_size,
                              hipStream_t stream) {
    const float* L     = (const float*)d_in[0];
    const float* x     = (const float*)d_in[1];
    const float* theta = (const float*)d_in[2];
    const float* bias  = (const float*)d_in[3];
    float* y = (float*)d_out;

    const size_t TE = (size_t)CIN * NN;
    const size_t LE = (size_t)NN * NN;

    // ws: Lb tiled (128MB) | Tf1..Tf3 (1MB ea) | Tb0..Tb3 (0.5MB ea) | part (2MB)
    char*  LbC = (char*)d_ws;
    float* Tf1 = (float*)(LbC + LE * 2);
    float* Tf2 = Tf1 + TE;
    float* Tf3 = Tf2 + TE;
    short* Tb0 = (short*)(Tf3 + TE);
    short* Tb1 = Tb0 + TE;
    short* Tb2 = Tb1 + TE;
    short* Tb3 = Tb2 + TE;
    float* part = (float*)(Tb3 + TE);

    cvt_kernel<<<256, 256, 0, stream>>>(x, Tb0);
    pass1_kernel<<<NN / 8, 512, 0, stream>>>(L, Tb0, LbC, part);
    combine1_kernel<<<256, 256, 0, stream>>>(part, Tf1, Tb1);
    passmid_kernel<<<NN / 16, 512, 0, stream>>>(LbC, Tb1, x,   Tf2, Tb2);  // T2
    passmid_kernel<<<NN / 16, 512, 0, stream>>>(LbC, Tb2, Tf1, Tf3, Tb3);  // T3
    pass4_kernel<<<NN / 16, 512, 0, stream>>>(LbC, Tb3, Tf2, x, Tf1, Tf3,
                                              theta, bias, y);             // T4 + einsum
}

// Round 16
// 218.906 us; speedup vs baseline: 1.2062x; 1.1172x over previous
//
#include <hip/hip_runtime.h>

#define NN 8192
#define CIN 32
#define COUT 64
#define KF 5

typedef __attribute__((ext_vector_type(8))) short bf16x8_t;
typedef __attribute__((ext_vector_type(4))) float f32x4_t;

typedef const __attribute__((address_space(1))) void* as1_t;
typedef __attribute__((address_space(3))) void* as3_t;
__device__ __forceinline__ void gll16(const void* g, void* l) {
    __builtin_amdgcn_global_load_lds((as1_t)g, (as3_t)l, 16, 0, 0);
}

// fp32 -> bf16 RNE
__device__ __forceinline__ short f2bf(float f) {
    unsigned u = __builtin_bit_cast(unsigned, f);
    unsigned r = (u + 0x7FFFu + ((u >> 16) & 1u)) >> 16;
    return (short)(unsigned short)r;
}

// x fp32 -> bf16
__global__ void cvt_kernel(const float* __restrict__ src, short* __restrict__ dst) {
    int idx = blockIdx.x * 256 + threadIdx.x;
    float4 v = reinterpret_cast<const float4*>(src)[idx];
    short4 o;
    o.x = f2bf(v.x); o.y = f2bf(v.y); o.z = f2bf(v.z); o.w = f2bf(v.w);
    reinterpret_cast<short4*>(dst)[idx] = o;
}

// D layout (m89): col=lane&15 -> i, row=(lane>>4)*4+reg -> c
__device__ __forceinline__ void stash_partials(float* red, int wave, int g, int r,
                                               const f32x4_t& acc0, const f32x4_t& acc1) {
    const int base = wave * 512 + g * 64 + r;
#pragma unroll
    for (int t = 0; t < 4; ++t) {
        red[base + t * 16]       = acc0[t];
        red[base + t * 16 + 256] = acc1[t];
    }
}

__device__ __forceinline__ float reduce8(const float* red, int tid) {
    float s = red[tid];
#pragma unroll
    for (int w = 1; w < 8; ++w) s += red[w * 512 + tid];
    return s;
}

// ---- Pass 1 v3: block = (tile t, panel p of 1024 cols).
// Stage: each wave reads 2 rows x 4KB contiguous (NT), cvt -> XOR-swizzled LDS image
//   (tiled chunk layout: byte = chunk*2048 + kk*1024 + g*256 + r*16 + half,
//    sw = byte ^ ((byte>>8)&0xF)<<4).
// Then: linear 32KB dump -> Lb (tiled layout mids consume) + T1 partial MFMA
//   (B from image, A from L2-resident Tb0), part[p] per panel.
__global__ __launch_bounds__(512, 2) void pass1_kernel(
    const float* __restrict__ L, const short* __restrict__ Tb0,
    char* __restrict__ LbC, float* __restrict__ part)
{
    __shared__ float red[4096];                 // 16 KB
    __shared__ __align__(16) char img[32768];   // 32 KB bf16 panel image (swizzled)
    const int tid = threadIdx.x, wave = tid >> 6, lane = tid & 63;
    const int t = blockIdx.x >> 3, p = blockIdx.x & 7;
    const int i0 = t * 16, kp = p * 1024;

    // ---- Stage phase
    {
        const int chunk_lo = lane >> 4;          // 0..3 within a seg
        const int kk = (lane >> 3) & 1;
        const int g = (lane >> 1) & 3;
        const int half = (lane & 1) * 8;
#pragma unroll
        for (int rr = 0; rr < 2; ++rr) {
            const int r = wave * 2 + rr;
            const float* src = L + (size_t)(i0 + r) * NN + kp + lane * 4;
#pragma unroll
            for (int seg = 0; seg < 4; ++seg) {
                f32x4_t v = __builtin_nontemporal_load(
                    reinterpret_cast<const f32x4_t*>(src + seg * 256));
                short4 b4;
                b4.x = f2bf(v[0]); b4.y = f2bf(v[1]); b4.z = f2bf(v[2]); b4.w = f2bf(v[3]);
                const int chunk = seg * 4 + chunk_lo;
                const int byte = chunk * 2048 + kk * 1024 + g * 256 + r * 16 + half;
                const int sw = byte ^ (((byte >> 8) & 0xF) << 4);
                *reinterpret_cast<short4*>(img + sw) = b4;
            }
        }
    }
    __syncthreads();

    // ---- Dump: img -> Lb, fully linear 32KB (unswizzle on LDS read)
    {
        char* dst = LbC + (size_t)t * 262144 + p * 32768;
#pragma unroll
        for (int i = 0; i < 4; ++i) {
            const int b = tid * 16 + i * 8192;
            const int sw = b ^ (((b >> 8) & 0xF) << 4);
            *reinterpret_cast<f32x4_t*>(dst + b) =
                *reinterpret_cast<const f32x4_t*>(img + sw);
        }
    }

    // ---- T1 partial MFMA: wave covers chunks 2w, 2w+1 of the panel
    const int g = lane >> 4, r = lane & 15;
    const short* A0 = Tb0 + (size_t)r * NN + kp;
    const short* A1 = Tb0 + (size_t)(r + 16) * NN + kp;
    f32x4_t acc0 = {0.f,0.f,0.f,0.f}, acc1 = {0.f,0.f,0.f,0.f};
#pragma unroll
    for (int cc = 0; cc < 2; ++cc) {
        const int chunk = wave * 2 + cc;
#pragma unroll
        for (int kk = 0; kk < 2; ++kk) {
            const int byte = chunk * 2048 + kk * 1024 + g * 256 + r * 16;
            const int sw = byte ^ (((byte >> 8) & 0xF) << 4);
            bf16x8_t b = *reinterpret_cast<const bf16x8_t*>(img + sw);
            const int ja = chunk * 64 + kk * 32 + g * 8;
            bf16x8_t a0 = *reinterpret_cast<const bf16x8_t*>(A0 + ja);
            bf16x8_t a1 = *reinterpret_cast<const bf16x8_t*>(A1 + ja);
            acc0 = __builtin_amdgcn_mfma_f32_16x16x32_bf16(a0, b, acc0, 0, 0, 0);
            acc1 = __builtin_amdgcn_mfma_f32_16x16x32_bf16(a1, b, acc1, 0, 0, 0);
        }
    }
    stash_partials(red, wave, g, r, acc0, acc1);
    __syncthreads();
    const int c = tid >> 4, il = tid & 15;
    part[(size_t)p * CIN * NN + (size_t)c * NN + i0 + il] = reduce8(red, tid);
}

// ---- T1 = sum of 8 panel partials (fixed order); write fp32 + bf16
__global__ __launch_bounds__(256) void combine8_kernel(
    const float* __restrict__ part, float* __restrict__ Tf1, short* __restrict__ Tb1)
{
    const int idx = blockIdx.x * 256 + threadIdx.x;   // quad index, CIN*NN/4
    const int NQ = CIN * NN / 4;
    float4 s = reinterpret_cast<const float4*>(part)[idx];
#pragma unroll
    for (int t = 1; t < 8; ++t) {
        float4 v = reinterpret_cast<const float4*>(part)[(size_t)t * NQ + idx];
        s.x += v.x; s.y += v.y; s.z += v.z; s.w += v.w;
    }
    reinterpret_cast<float4*>(Tf1)[idx] = s;
    short4 b;
    b.x = f2bf(s.x); b.y = f2bf(s.y); b.z = f2bf(s.z); b.w = f2bf(s.w);
    reinterpret_cast<short4*>(Tb1)[idx] = b;
}

// Mid-pass core (R15): L via depth-2 DMA ring (2KB/chunk), A via plain VGPR loads.
__device__ __forceinline__ void mid_core(const char* __restrict__ LbW,
                                         const short* __restrict__ Abase,
                                         int wave, int lane, char* stg,
                                         f32x4_t& acc0, f32x4_t& acc1)
{
    const int g = lane >> 4, r = lane & 15;
    const int kw = wave * 1024;
    const char* srcL = LbW + lane * 16;
    const short* A0 = Abase + (size_t)r * NN        + kw + g * 8;
    const short* A1 = Abase + (size_t)(r + 16) * NN + kw + g * 8;

    gll16(srcL + 0,    stg + 0);
    gll16(srcL + 1024, stg + 1024);
    gll16(srcL + 2048, stg + 2048);
    gll16(srcL + 3072, stg + 3072);

    for (int c = 0; c < 16; ++c) {
        if (c < 15) asm volatile("s_waitcnt vmcnt(2)" ::: "memory");
        else        asm volatile("s_waitcnt vmcnt(0)" ::: "memory");
        const char* Ld = stg + (c & 1) * 2048;
#pragma unroll
        for (int kk = 0; kk < 2; ++kk) {
            bf16x8_t b  = *(const bf16x8_t*)(Ld + (kk * 4 + g) * 256 + r * 16);
            bf16x8_t a0 = *(const bf16x8_t*)(A0 + c * 64 + kk * 32);
            bf16x8_t a1 = *(const bf16x8_t*)(A1 + c * 64 + kk * 32);
            acc0 = __builtin_amdgcn_mfma_f32_16x16x32_bf16(a0, b, acc0, 0, 0, 0);
            acc1 = __builtin_amdgcn_mfma_f32_16x16x32_bf16(a1, b, acc1, 0, 0, 0);
        }
        if (c < 14) {
            asm volatile("s_waitcnt lgkmcnt(0)" ::: "memory");
            const int cn = c + 2;
            gll16(srcL + cn * 2048,        stg + (cn & 1) * 2048);
            gll16(srcL + cn * 2048 + 1024, stg + (cn & 1) * 2048 + 1024);
        }
    }
}

// ---- Mid passes (2,3): T_next = 2*(Tcur @ Lb^T) - Tprev
__global__ __launch_bounds__(512, 4) void passmid_kernel(
    const char* __restrict__ LbC, const short* __restrict__ A,
    const float* __restrict__ Tprev, float* __restrict__ Tf, short* __restrict__ Tb)
{
    __shared__ float red[4096];
    __shared__ __align__(16) char stg[8][4096];
    const int tid = threadIdx.x, wave = tid >> 6, lane = tid & 63;
    const int g = lane >> 4, r = lane & 15;
    const int t = blockIdx.x, i0 = t * 16;

    f32x4_t acc0 = {0.f,0.f,0.f,0.f}, acc1 = {0.f,0.f,0.f,0.f};
    mid_core(LbC + (size_t)t * 262144 + wave * 32768, A, wave, lane, stg[wave], acc0, acc1);

    stash_partials(red, wave, g, r, acc0, acc1);
    __syncthreads();
    const int c = tid >> 4, il = tid & 15;
    const size_t off = (size_t)c * NN + i0 + il;
    const float val = 2.0f * reduce8(red, tid) - Tprev[off];
    Tf[off] = val;
    Tb[off] = f2bf(val);
}

// ---- Pass 4 + fused final einsum (T4 stays in LDS)
__global__ __launch_bounds__(512, 4) void pass4_kernel(
    const char* __restrict__ LbC, const short* __restrict__ A,
    const float* __restrict__ Tf2, const float* __restrict__ x,
    const float* __restrict__ Tf1, const float* __restrict__ Tf3,
    const float* __restrict__ theta, const float* __restrict__ bias,
    float* __restrict__ y)
{
    __shared__ float red[4096];
    __shared__ __align__(16) char stg[8][4096];
    const int tid = threadIdx.x, wave = tid >> 6, lane = tid & 63;
    const int g = lane >> 4, r = lane & 15;
    const int t = blockIdx.x, i0 = t * 16;

    f32x4_t acc0 = {0.f,0.f,0.f,0.f}, acc1 = {0.f,0.f,0.f,0.f};
    mid_core(LbC + (size_t)t * 262144 + wave * 32768, A, wave, lane, stg[wave], acc0, acc1);

    stash_partials(red, wave, g, r, acc0, acc1);
    __syncthreads();
    {   // T4 column -> red[tid] (own-slot overwrite, safe)
        const int c = tid >> 4, il = tid & 15;
        red[tid] = 2.0f * reduce8(red, tid) - Tf2[(size_t)c * NN + i0 + il];
    }
    __syncthreads();

    const int o = tid >> 4, il = tid & 15;
    float a0 = bias[o], a1 = bias[o + 32];
    for (int cc = 0; cc < CIN; ++cc) {
        const size_t off = (size_t)cc * NN + i0 + il;
        const float t0 = x[off], t1 = Tf1[off], t2 = Tf2[off], t3 = Tf3[off];
        const float t4 = red[cc * 16 + il];
        const float* th0 = theta + ((size_t)o * CIN + cc) * KF;
        const float* th1 = theta + ((size_t)(o + 32) * CIN + cc) * KF;
        a0 += t0 * th0[0] + t1 * th0[1] + t2 * th0[2] + t3 * th0[3] + t4 * th0[4];
        a1 += t0 * th1[0] + t1 * th1[1] + t2 * th1[2] + t3 * th1[3] + t4 * th1[4];
    }
    y[(size_t)o * NN + i0 + il]        = a0;
    y[(size_t)(o + 32) * NN + i0 + il] = a1;
}

extern "C" void kernel_launch(void* const* d_in, const int* in_sizes, int n_in,
                              void* d_out, int out_size, void* d_ws, size_t ws_size,
                              hipStream_t stream) {
    const float* L     = (const float*)d_in[0];
    const float* x     = (const float*)d_in[1];
    const float* theta = (const float*)d_in[2];
    const float* bias  = (const float*)d_in[3];
    float* y = (float*)d_out;

    const size_t TE = (size_t)CIN * NN;
    const size_t LE = (size_t)NN * NN;

    // ws: Lb tiled (128MB) | Tf1..Tf3 (1MB ea) | Tb0..Tb3 (0.5MB ea) | part (8MB)
    char*  LbC = (char*)d_ws;
    float* Tf1 = (float*)(LbC + LE * 2);
    float* Tf2 = Tf1 + TE;
    float* Tf3 = Tf2 + TE;
    short* Tb0 = (short*)(Tf3 + TE);
    short* Tb1 = Tb0 + TE;
    short* Tb2 = Tb1 + TE;
    short* Tb3 = Tb2 + TE;
    float* part = (float*)(Tb3 + TE);

    cvt_kernel<<<256, 256, 0, stream>>>(x, Tb0);
    pass1_kernel<<<(NN / 16) * 8, 512, 0, stream>>>(L, Tb0, LbC, part);
    combine8_kernel<<<256, 256, 0, stream>>>(part, Tf1, Tb1);
    passmid_kernel<<<NN / 16, 512, 0, stream>>>(LbC, Tb1, x,   Tf2, Tb2);  // T2
    passmid_kernel<<<NN / 16, 512, 0, stream>>>(LbC, Tb2, Tf1, Tf3, Tb3);  // T3
    pass4_kernel<<<NN / 16, 512, 0, stream>>>(LbC, Tb3, Tf2, x, Tf1, Tf3,
                                              theta, bias, y);             // T4 + einsum
}